// Round 2
// baseline (3065.198 us; speedup 1.0000x reference)
//
#include <hip/hip_runtime.h>

#define HIDDIM 256
#define NHEADS 8

__device__ __forceinline__ unsigned fenc(float f) {
  unsigned u = __float_as_uint(f);
  return (u & 0x80000000u) ? ~u : (u | 0x80000000u);
}
__device__ __forceinline__ float fdec(unsigned u) {
  return (u & 0x80000000u) ? __uint_as_float(u ^ 0x80000000u) : __uint_as_float(~u);
}

// C[M,N] = act(A[M,K] @ W[K,N] + bias[N]); act: 0=none, 1=relu
__global__ __launch_bounds__(256) void gemm_bias_act(
    const float* __restrict__ A, const float* __restrict__ W,
    const float* __restrict__ bias, float* __restrict__ C,
    int M, int N, int K, int act) {
  __shared__ float As[16][65];
  __shared__ float Bs[16][64];
  const int tid = threadIdx.x;
  const int bm = blockIdx.y * 64, bn = blockIdx.x * 64;
  const int tx = tid & 15, ty = tid >> 4;
  float acc[4][4] = {};
  for (int k0 = 0; k0 < K; k0 += 16) {
    {
      const int m = tid >> 2;           // 0..63
      const int k = (tid & 3) * 4;      // 0,4,8,12
      const int gm = bm + m;
      float4 v = make_float4(0.f, 0.f, 0.f, 0.f);
      if (gm < M) v = *(const float4*)(A + (size_t)gm * K + k0 + k);
      As[k + 0][m] = v.x; As[k + 1][m] = v.y; As[k + 2][m] = v.z; As[k + 3][m] = v.w;
    }
    {
      const int n = (tid & 15) * 4;
      const int k = tid >> 4;
      *(float4*)&Bs[k][n] = *(const float4*)(W + (size_t)(k0 + k) * N + bn + n);
    }
    __syncthreads();
    #pragma unroll
    for (int kk = 0; kk < 16; ++kk) {
      float a[4], b[4];
      #pragma unroll
      for (int i = 0; i < 4; ++i) a[i] = As[kk][ty * 4 + i];
      #pragma unroll
      for (int j = 0; j < 4; ++j) b[j] = Bs[kk][tx * 4 + j];
      #pragma unroll
      for (int i = 0; i < 4; ++i)
        #pragma unroll
        for (int j = 0; j < 4; ++j) acc[i][j] = fmaf(a[i], b[j], acc[i][j]);
    }
    __syncthreads();
  }
  #pragma unroll
  for (int i = 0; i < 4; ++i) {
    const int gm = bm + ty * 4 + i;
    if (gm >= M) continue;
    #pragma unroll
    for (int j = 0; j < 4; ++j) {
      const int gn = bn + tx * 4 + j;
      float v = acc[i][j] + bias[gn];
      if (act == 1 && v < 0.f) v = 0.f;
      C[(size_t)gm * N + gn] = v;
    }
  }
}

// one wave per edge; lane covers channels [4*lane, 4*lane+4); head = lane>>3
__global__ __launch_bounds__(256) void edge_score(
    const float* __restrict__ xl, const float* __restrict__ xr,
    const int* __restrict__ ei, const float* __restrict__ att,
    float* __restrict__ score, unsigned* __restrict__ smax, int E, int Nn) {
  const int ET = E + Nn;
  const int e = (int)((blockIdx.x * (size_t)blockDim.x + threadIdx.x) >> 6);
  const int lane = threadIdx.x & 63;
  if (e >= ET) return;
  int src, dst;
  if (e < E) { src = ei[e]; dst = ei[E + e]; }
  else { src = e - E; dst = e - E; }
  const float4 a = *(const float4*)(xl + (size_t)src * HIDDIM + lane * 4);
  const float4 b = *(const float4*)(xr + (size_t)dst * HIDDIM + lane * 4);
  const float4 at = *(const float4*)(att + lane * 4);
  float s = 0.f;
  {
    float v;
    v = a.x + b.x; v = v >= 0.f ? v : 0.2f * v; s = fmaf(v, at.x, s);
    v = a.y + b.y; v = v >= 0.f ? v : 0.2f * v; s = fmaf(v, at.y, s);
    v = a.z + b.z; v = v >= 0.f ? v : 0.2f * v; s = fmaf(v, at.z, s);
    v = a.w + b.w; v = v >= 0.f ? v : 0.2f * v; s = fmaf(v, at.w, s);
  }
  s += __shfl_xor(s, 1);
  s += __shfl_xor(s, 2);
  s += __shfl_xor(s, 4);
  if ((lane & 7) == 0) {
    const int h = lane >> 3;
    score[(size_t)e * NHEADS + h] = s;
    atomicMax(&smax[dst * NHEADS + h], fenc(s));
  }
}

// one thread per (edge, head): ex = exp(score - max); denom += ex
__global__ __launch_bounds__(256) void edge_exp(
    float* __restrict__ score, const unsigned* __restrict__ smax,
    const int* __restrict__ ei, float* __restrict__ denom, int E, int Nn) {
  const size_t idx = blockIdx.x * (size_t)blockDim.x + threadIdx.x;
  const int ET = E + Nn;
  if (idx >= (size_t)ET * NHEADS) return;
  const int e = (int)(idx >> 3);
  const int h = (int)(idx & 7);
  const int dst = (e < E) ? ei[E + e] : (e - E);
  const float m = fdec(smax[dst * NHEADS + h]);
  const float ex = expf(score[idx] - m);
  score[idx] = ex;
  atomicAdd(&denom[dst * NHEADS + h], ex);
}

// one wave per edge: agg[dst] += alpha * xl[src]
__global__ __launch_bounds__(256) void edge_aggregate(
    const float* __restrict__ xl, const float* __restrict__ score,
    const float* __restrict__ denom, const int* __restrict__ ei,
    float* __restrict__ agg, int E, int Nn) {
  const int ET = E + Nn;
  const int e = (int)((blockIdx.x * (size_t)blockDim.x + threadIdx.x) >> 6);
  const int lane = threadIdx.x & 63;
  if (e >= ET) return;
  int src, dst;
  if (e < E) { src = ei[e]; dst = ei[E + e]; }
  else { src = e - E; dst = e - E; }
  const int h = lane >> 3;
  const float alpha = score[(size_t)e * NHEADS + h] / denom[dst * NHEADS + h];
  const float4 v = *(const float4*)(xl + (size_t)src * HIDDIM + lane * 4);
  float* o = agg + (size_t)dst * HIDDIM + lane * 4;
  atomicAdd(o + 0, alpha * v.x);
  atomicAdd(o + 1, alpha * v.y);
  atomicAdd(o + 2, alpha * v.z);
  atomicAdd(o + 3, alpha * v.w);
}

// h0 = layernorm(relu(agg + bias)) ; one wave per node row
__global__ __launch_bounds__(256) void epilogue_ln(
    const float* __restrict__ agg, const float* __restrict__ bias,
    const float* __restrict__ lng, const float* __restrict__ lnb,
    float* __restrict__ outp, int Nn) {
  const int n = (int)((blockIdx.x * (size_t)blockDim.x + threadIdx.x) >> 6);
  const int lane = threadIdx.x & 63;
  if (n >= Nn) return;
  const float4 v = *(const float4*)(agg + (size_t)n * HIDDIM + lane * 4);
  const float4 bb = *(const float4*)(bias + lane * 4);
  float t0 = v.x + bb.x; t0 = t0 > 0.f ? t0 : 0.f;
  float t1 = v.y + bb.y; t1 = t1 > 0.f ? t1 : 0.f;
  float t2 = v.z + bb.z; t2 = t2 > 0.f ? t2 : 0.f;
  float t3 = v.w + bb.w; t3 = t3 > 0.f ? t3 : 0.f;
  float s = t0 + t1 + t2 + t3;
  #pragma unroll
  for (int m = 1; m < 64; m <<= 1) s += __shfl_xor(s, m);
  const float mu = s * (1.f / HIDDIM);
  float d0 = t0 - mu, d1 = t1 - mu, d2 = t2 - mu, d3 = t3 - mu;
  float q = d0 * d0 + d1 * d1 + d2 * d2 + d3 * d3;
  #pragma unroll
  for (int m = 1; m < 64; m <<= 1) q += __shfl_xor(q, m);
  const float inv = rsqrtf(q * (1.f / HIDDIM) + 1e-5f);
  const float4 g4 = *(const float4*)(lng + lane * 4);
  const float4 b4 = *(const float4*)(lnb + lane * 4);
  float4 o;
  o.x = d0 * inv * g4.x + b4.x;
  o.y = d1 * inv * g4.y + b4.y;
  o.z = d2 * inv * g4.z + b4.z;
  o.w = d3 * inv * g4.w + b4.w;
  *(float4*)(outp + (size_t)n * HIDDIM + lane * 4) = o;
}

// pooled[batch[n]] += relu(agg[n] + bias); counts[g] += 1 ; one wave per node
__global__ __launch_bounds__(256) void epilogue_pool(
    const float* __restrict__ agg, const float* __restrict__ bias,
    const int* __restrict__ batch, float* __restrict__ pooled,
    float* __restrict__ counts, int Nn) {
  const int n = (int)((blockIdx.x * (size_t)blockDim.x + threadIdx.x) >> 6);
  const int lane = threadIdx.x & 63;
  if (n >= Nn) return;
  const int g = batch[n];
  const float4 v = *(const float4*)(agg + (size_t)n * HIDDIM + lane * 4);
  const float4 bb = *(const float4*)(bias + lane * 4);
  float t0 = v.x + bb.x; t0 = t0 > 0.f ? t0 : 0.f;
  float t1 = v.y + bb.y; t1 = t1 > 0.f ? t1 : 0.f;
  float t2 = v.z + bb.z; t2 = t2 > 0.f ? t2 : 0.f;
  float t3 = v.w + bb.w; t3 = t3 > 0.f ? t3 : 0.f;
  float* p = pooled + (size_t)g * HIDDIM + lane * 4;
  atomicAdd(p + 0, t0);
  atomicAdd(p + 1, t1);
  atomicAdd(p + 2, t2);
  atomicAdd(p + 3, t3);
  if (lane == 0) atomicAdd(&counts[g], 1.f);
}

// single block: out = relu(pooled_mean @ h1_w + h1_b) @ h2_w + h2_b
__global__ __launch_bounds__(256) void head_kernel(
    const float* __restrict__ pooled, const float* __restrict__ counts,
    const float* __restrict__ h1w, const float* __restrict__ h1b,
    const float* __restrict__ h2w, const float* __restrict__ h2b,
    float* __restrict__ out, int G, int H1, int OUT) {
  __shared__ float P[16][HIDDIM];
  __shared__ float Hh[16][128];
  const int tid = threadIdx.x;
  for (int i = tid; i < G * HIDDIM; i += 256) {
    const int g = i / HIDDIM, c = i % HIDDIM;
    float cnt = counts[g];
    if (cnt < 1.f) cnt = 1.f;
    P[g][c] = pooled[i] / cnt;
  }
  __syncthreads();
  for (int i = tid; i < G * H1; i += 256) {
    const int g = i / H1, j = i % H1;
    float s = h1b[j];
    for (int k = 0; k < HIDDIM; ++k) s = fmaf(P[g][k], h1w[k * H1 + j], s);
    Hh[g][j] = s > 0.f ? s : 0.f;
  }
  __syncthreads();
  for (int i = tid; i < G * OUT; i += 256) {
    const int g = i / OUT, o = i % OUT;
    float s = h2b[o];
    for (int k = 0; k < H1; ++k) s = fmaf(Hh[g][k], h2w[k * OUT + o], s);
    out[i] = s;
  }
}

extern "C" void kernel_launch(void* const* d_in, const int* in_sizes, int n_in,
                              void* d_out, int out_size, void* d_ws, size_t ws_size,
                              hipStream_t stream) {
  const float* x = (const float*)d_in[0];
  const int* ei = (const int*)d_in[1];      // int inputs arrive as int32
  const int* batch = (const int*)d_in[2];
  const float* enc_w = (const float*)d_in[3];
  const float* enc_b = (const float*)d_in[4];
  const float* g_wl[2] = {(const float*)d_in[5], (const float*)d_in[11]};
  const float* g_bl[2] = {(const float*)d_in[6], (const float*)d_in[12]};
  const float* g_wr[2] = {(const float*)d_in[7], (const float*)d_in[13]};
  const float* g_br[2] = {(const float*)d_in[8], (const float*)d_in[14]};
  const float* g_att[2] = {(const float*)d_in[9], (const float*)d_in[15]};
  const float* g_bias[2] = {(const float*)d_in[10], (const float*)d_in[16]};
  const float* ln_g = (const float*)d_in[17];
  const float* ln_b = (const float*)d_in[18];
  const float* h1_w = (const float*)d_in[19];
  const float* h1_b = (const float*)d_in[20];
  const float* h2_w = (const float*)d_in[21];
  const float* h2_b = (const float*)d_in[22];
  float* out = (float*)d_out;

  const int N = in_sizes[2];          // 20000
  const int E = in_sizes[1] / 2;      // 320000
  const int DIN = in_sizes[0] / N;    // 128
  const int ET = E + N;               // edges + self-loops
  const int H1 = in_sizes[20];        // 128
  const int OUT = in_sizes[22];       // 2
  const int G = out_size / OUT;       // 16

  float* ws = (float*)d_ws;
  const size_t NH = (size_t)N * HIDDIM;
  float* h0 = ws;                      // features (ping)
  float* xl = h0 + NH;
  float* xr = xl + NH;
  float* agg = xr;                     // alias: xr dead after edge_score
  float* escore = xr + NH;             // [ET, 8]
  unsigned* smax = (unsigned*)(escore + (size_t)ET * NHEADS);  // [N,8]
  float* denom = (float*)smax + (size_t)N * NHEADS;            // [N,8]
  float* pooled = denom + (size_t)N * NHEADS;                  // [G,256]
  float* counts = pooled + (size_t)G * HIDDIM;                 // [G]

  const dim3 blk(256);
  const dim3 gemm_grid(HIDDIM / 64, (N + 63) / 64);
  const int eb = (ET + 3) / 4;
  const int xb = (int)(((size_t)ET * NHEADS + 255) / 256);
  const int nb = (N + 3) / 4;

  // encoder: h0 = relu(x @ enc_w + enc_b)
  gemm_bias_act<<<gemm_grid, blk, 0, stream>>>(x, enc_w, enc_b, h0, N, HIDDIM, DIN, 1);

  hipMemsetAsync(pooled, 0, ((size_t)G * HIDDIM + G) * sizeof(float), stream);

  for (int L = 0; L < 2; ++L) {
    gemm_bias_act<<<gemm_grid, blk, 0, stream>>>(h0, g_wl[L], g_bl[L], xl, N, HIDDIM, HIDDIM, 0);
    gemm_bias_act<<<gemm_grid, blk, 0, stream>>>(h0, g_wr[L], g_br[L], xr, N, HIDDIM, HIDDIM, 0);
    hipMemsetAsync(smax, 0, (size_t)N * NHEADS * 2 * sizeof(float), stream);  // smax + denom
    edge_score<<<eb, blk, 0, stream>>>(xl, xr, ei, g_att[L], escore, smax, E, N);
    hipMemsetAsync(agg, 0, NH * sizeof(float), stream);  // xr dead now; reuse as agg
    edge_exp<<<xb, blk, 0, stream>>>(escore, smax, ei, denom, E, N);
    edge_aggregate<<<eb, blk, 0, stream>>>(xl, escore, denom, ei, agg, E, N);
    if (L == 0) {
      epilogue_ln<<<nb, blk, 0, stream>>>(agg, g_bias[0], ln_g, ln_b, h0, N);
    } else {
      epilogue_pool<<<nb, blk, 0, stream>>>(agg, g_bias[1], batch, pooled, counts, N);
    }
  }
  head_kernel<<<1, blk, 0, stream>>>(pooled, counts, h1_w, h1_b, h2_w, h2_b, out, G, H1, OUT);
}

// Round 3
// 852.879 us; speedup vs baseline: 3.5939x; 3.5939x over previous
//
#include <hip/hip_runtime.h>

#define HIDDIM 256
#define NHEADS 8

// ---------------- GEMM: C[M,N] = act(A[M,K] @ W[K,N] + bias[N]) ----------------
__global__ __launch_bounds__(256) void gemm_bias_act(
    const float* __restrict__ A, const float* __restrict__ W,
    const float* __restrict__ bias, float* __restrict__ C,
    int M, int N, int K, int act) {
  __shared__ float As[16][65];
  __shared__ float Bs[16][64];
  const int tid = threadIdx.x;
  const int bm = blockIdx.y * 64, bn = blockIdx.x * 64;
  const int tx = tid & 15, ty = tid >> 4;
  float acc[4][4] = {};
  for (int k0 = 0; k0 < K; k0 += 16) {
    {
      const int m = tid >> 2;
      const int k = (tid & 3) * 4;
      const int gm = bm + m;
      float4 v = make_float4(0.f, 0.f, 0.f, 0.f);
      if (gm < M) v = *(const float4*)(A + (size_t)gm * K + k0 + k);
      As[k + 0][m] = v.x; As[k + 1][m] = v.y; As[k + 2][m] = v.z; As[k + 3][m] = v.w;
    }
    {
      const int n = (tid & 15) * 4;
      const int k = tid >> 4;
      *(float4*)&Bs[k][n] = *(const float4*)(W + (size_t)(k0 + k) * N + bn + n);
    }
    __syncthreads();
    #pragma unroll
    for (int kk = 0; kk < 16; ++kk) {
      float a[4], b[4];
      #pragma unroll
      for (int i = 0; i < 4; ++i) a[i] = As[kk][ty * 4 + i];
      #pragma unroll
      for (int j = 0; j < 4; ++j) b[j] = Bs[kk][tx * 4 + j];
      #pragma unroll
      for (int i = 0; i < 4; ++i)
        #pragma unroll
        for (int j = 0; j < 4; ++j) acc[i][j] = fmaf(a[i], b[j], acc[i][j]);
    }
    __syncthreads();
  }
  #pragma unroll
  for (int i = 0; i < 4; ++i) {
    const int gm = bm + ty * 4 + i;
    if (gm >= M) continue;
    #pragma unroll
    for (int j = 0; j < 4; ++j) {
      const int gn = bn + tx * 4 + j;
      float v = acc[i][j] + bias[gn];
      if (act == 1 && v < 0.f) v = 0.f;
      C[(size_t)gm * N + gn] = v;
    }
  }
}

// ---------------- CSR build (by destination) ----------------
__global__ __launch_bounds__(256) void count_deg(
    const int* __restrict__ ei, int* __restrict__ deg, int E, int Nn) {
  const int t = blockIdx.x * blockDim.x + threadIdx.x;
  const int ET = E + Nn;
  if (t >= ET) return;
  const int dst = (t < E) ? ei[E + t] : (t - E);
  atomicAdd(&deg[dst], 1);
}

__global__ __launch_bounds__(1024) void scan_deg(
    const int* __restrict__ deg, int* __restrict__ rowptr, int Nn) {
  __shared__ int lds[1024];
  __shared__ int carry;
  const int tid = threadIdx.x;
  if (tid == 0) { carry = 0; rowptr[0] = 0; }
  __syncthreads();
  for (int base = 0; base < Nn; base += 1024) {
    const int i = base + tid;
    int v = (i < Nn) ? deg[i] : 0;
    lds[tid] = v;
    __syncthreads();
    for (int off = 1; off < 1024; off <<= 1) {
      int t = (tid >= off) ? lds[tid - off] : 0;
      __syncthreads();
      lds[tid] += t;
      __syncthreads();
    }
    const int incl = lds[tid];
    const int c = carry;
    if (i < Nn) rowptr[i + 1] = incl + c;
    __syncthreads();
    if (tid == 0) carry = c + lds[1023];
    __syncthreads();
  }
}

__global__ __launch_bounds__(256) void fill_csr(
    const int* __restrict__ ei, const int* __restrict__ rowptr,
    int* __restrict__ cursor, int* __restrict__ csr, int E, int Nn) {
  const int t = blockIdx.x * blockDim.x + threadIdx.x;
  const int ET = E + Nn;
  if (t >= ET) return;
  const int dst = (t < E) ? ei[E + t] : (t - E);
  const int pos = atomicAdd(&cursor[dst], 1);
  csr[rowptr[dst] + pos] = t;
}

// ---------------- fused GATv2 per-node kernel ----------------
// one wave per node; lane covers channels [4*lane, 4*lane+4); head h = lane>>3
// MODE 0: out = layernorm(relu(agg + bias)) -> outp[n]
// MODE 1: pooled[batch[n]] += relu(agg + bias); counts += 1
template <int MODE>
__global__ __launch_bounds__(256) void node_gat(
    const float* __restrict__ xl, const float* __restrict__ xr,
    const int* __restrict__ ei, const int* __restrict__ rowptr,
    const int* __restrict__ csr, const float* __restrict__ att,
    const float* __restrict__ bias,
    const float* __restrict__ lng, const float* __restrict__ lnb,
    const int* __restrict__ batch, float* __restrict__ pooled,
    float* __restrict__ counts, float* __restrict__ outp, int E, int Nn) {
  const int n = (int)((blockIdx.x * (size_t)blockDim.x + threadIdx.x) >> 6);
  const int lane = threadIdx.x & 63;
  if (n >= Nn) return;
  const int r0 = rowptr[n], r1 = rowptr[n + 1];
  const float4 xr4 = *(const float4*)(xr + (size_t)n * HIDDIM + lane * 4);
  const float4 at4 = *(const float4*)(att + lane * 4);

  // phase 1: online softmax stats (m, d) per head; identical across the 8 lanes of a head group
  float m = -1e30f, d = 0.f;
  for (int j = r0; j < r1; ++j) {
    const int e = csr[j];
    const int src = (e < E) ? ei[e] : (e - E);
    const float4 a = *(const float4*)(xl + (size_t)src * HIDDIM + lane * 4);
    float v, s;
    v = a.x + xr4.x; v = v >= 0.f ? v : 0.2f * v; s = v * at4.x;
    v = a.y + xr4.y; v = v >= 0.f ? v : 0.2f * v; s = fmaf(v, at4.y, s);
    v = a.z + xr4.z; v = v >= 0.f ? v : 0.2f * v; s = fmaf(v, at4.z, s);
    v = a.w + xr4.w; v = v >= 0.f ? v : 0.2f * v; s = fmaf(v, at4.w, s);
    s += __shfl_xor(s, 1);
    s += __shfl_xor(s, 2);
    s += __shfl_xor(s, 4);
    const float mn = fmaxf(m, s);
    d = d * __expf(m - mn) + __expf(s - mn);
    m = mn;
  }
  const float inv_d = 1.f / d;

  // phase 2: recompute score from the same loads, accumulate alpha * xl[src]
  float4 acc = make_float4(0.f, 0.f, 0.f, 0.f);
  for (int j = r0; j < r1; ++j) {
    const int e = csr[j];
    const int src = (e < E) ? ei[e] : (e - E);
    const float4 a = *(const float4*)(xl + (size_t)src * HIDDIM + lane * 4);
    float v, s;
    v = a.x + xr4.x; v = v >= 0.f ? v : 0.2f * v; s = v * at4.x;
    v = a.y + xr4.y; v = v >= 0.f ? v : 0.2f * v; s = fmaf(v, at4.y, s);
    v = a.z + xr4.z; v = v >= 0.f ? v : 0.2f * v; s = fmaf(v, at4.z, s);
    v = a.w + xr4.w; v = v >= 0.f ? v : 0.2f * v; s = fmaf(v, at4.w, s);
    s += __shfl_xor(s, 1);
    s += __shfl_xor(s, 2);
    s += __shfl_xor(s, 4);
    const float alpha = __expf(s - m) * inv_d;
    acc.x = fmaf(alpha, a.x, acc.x);
    acc.y = fmaf(alpha, a.y, acc.y);
    acc.z = fmaf(alpha, a.z, acc.z);
    acc.w = fmaf(alpha, a.w, acc.w);
  }

  // epilogue: bias + relu
  const float4 bb = *(const float4*)(bias + lane * 4);
  float t0 = acc.x + bb.x; t0 = t0 > 0.f ? t0 : 0.f;
  float t1 = acc.y + bb.y; t1 = t1 > 0.f ? t1 : 0.f;
  float t2 = acc.z + bb.z; t2 = t2 > 0.f ? t2 : 0.f;
  float t3 = acc.w + bb.w; t3 = t3 > 0.f ? t3 : 0.f;

  if (MODE == 0) {
    float s = t0 + t1 + t2 + t3;
    #pragma unroll
    for (int mm = 1; mm < 64; mm <<= 1) s += __shfl_xor(s, mm);
    const float mu = s * (1.f / HIDDIM);
    const float d0 = t0 - mu, d1 = t1 - mu, d2 = t2 - mu, d3 = t3 - mu;
    float q = d0 * d0 + d1 * d1 + d2 * d2 + d3 * d3;
    #pragma unroll
    for (int mm = 1; mm < 64; mm <<= 1) q += __shfl_xor(q, mm);
    const float inv = rsqrtf(q * (1.f / HIDDIM) + 1e-5f);
    const float4 g4 = *(const float4*)(lng + lane * 4);
    const float4 b4 = *(const float4*)(lnb + lane * 4);
    float4 o;
    o.x = d0 * inv * g4.x + b4.x;
    o.y = d1 * inv * g4.y + b4.y;
    o.z = d2 * inv * g4.z + b4.z;
    o.w = d3 * inv * g4.w + b4.w;
    *(float4*)(outp + (size_t)n * HIDDIM + lane * 4) = o;
  } else {
    const int g = batch[n];
    float* p = pooled + (size_t)g * HIDDIM + lane * 4;
    atomicAdd(p + 0, t0);
    atomicAdd(p + 1, t1);
    atomicAdd(p + 2, t2);
    atomicAdd(p + 3, t3);
    if (lane == 0) atomicAdd(&counts[g], 1.f);
  }
}

// ---------------- head MLP ----------------
__global__ __launch_bounds__(256) void head_kernel(
    const float* __restrict__ pooled, const float* __restrict__ counts,
    const float* __restrict__ h1w, const float* __restrict__ h1b,
    const float* __restrict__ h2w, const float* __restrict__ h2b,
    float* __restrict__ out, int G, int H1, int OUT) {
  __shared__ float P[16][HIDDIM];
  __shared__ float Hh[16][128];
  const int tid = threadIdx.x;
  for (int i = tid; i < G * HIDDIM; i += 256) {
    const int g = i / HIDDIM, c = i % HIDDIM;
    float cnt = counts[g];
    if (cnt < 1.f) cnt = 1.f;
    P[g][c] = pooled[i] / cnt;
  }
  __syncthreads();
  for (int i = tid; i < G * H1; i += 256) {
    const int g = i / H1, j = i % H1;
    float s = h1b[j];
    for (int k = 0; k < HIDDIM; ++k) s = fmaf(P[g][k], h1w[k * H1 + j], s);
    Hh[g][j] = s > 0.f ? s : 0.f;
  }
  __syncthreads();
  for (int i = tid; i < G * OUT; i += 256) {
    const int g = i / OUT, o = i % OUT;
    float s = h2b[o];
    for (int k = 0; k < H1; ++k) s = fmaf(Hh[g][k], h2w[k * OUT + o], s);
    out[i] = s;
  }
}

extern "C" void kernel_launch(void* const* d_in, const int* in_sizes, int n_in,
                              void* d_out, int out_size, void* d_ws, size_t ws_size,
                              hipStream_t stream) {
  const float* x = (const float*)d_in[0];
  const int* ei = (const int*)d_in[1];
  const int* batch = (const int*)d_in[2];
  const float* enc_w = (const float*)d_in[3];
  const float* enc_b = (const float*)d_in[4];
  const float* g_wl[2] = {(const float*)d_in[5], (const float*)d_in[11]};
  const float* g_bl[2] = {(const float*)d_in[6], (const float*)d_in[12]};
  const float* g_wr[2] = {(const float*)d_in[7], (const float*)d_in[13]};
  const float* g_br[2] = {(const float*)d_in[8], (const float*)d_in[14]};
  const float* g_att[2] = {(const float*)d_in[9], (const float*)d_in[15]};
  const float* g_bias[2] = {(const float*)d_in[10], (const float*)d_in[16]};
  const float* ln_g = (const float*)d_in[17];
  const float* ln_b = (const float*)d_in[18];
  const float* h1_w = (const float*)d_in[19];
  const float* h1_b = (const float*)d_in[20];
  const float* h2_w = (const float*)d_in[21];
  const float* h2_b = (const float*)d_in[22];
  float* out = (float*)d_out;

  const int N = in_sizes[2];          // 20000
  const int E = in_sizes[1] / 2;      // 320000
  const int DIN = in_sizes[0] / N;    // 128
  const int ET = E + N;
  const int H1 = in_sizes[20];        // 128
  const int OUT = in_sizes[22];       // 2
  const int G = out_size / OUT;       // 16

  float* ws = (float*)d_ws;
  const size_t NH = (size_t)N * HIDDIM;
  float* h0 = ws;
  float* xl = h0 + NH;
  float* xr = xl + NH;
  float* pooled = xr + NH;                                  // [G,256]
  float* counts = pooled + (size_t)G * HIDDIM;              // [G]
  int* deg = (int*)(counts + G);                            // [N]
  int* rowptr = deg + N;                                    // [N+1]
  int* cursor = rowptr + (N + 1);                           // [N]
  int* csr = cursor + N;                                    // [ET]

  const dim3 blk(256);
  const dim3 gemm_grid(HIDDIM / 64, (N + 63) / 64);
  const int eb = (ET + 255) / 256;
  const int nb = (N + 3) / 4;

  // CSR build (graph identical for both layers)
  hipMemsetAsync(deg, 0, (size_t)N * sizeof(int), stream);
  hipMemsetAsync(cursor, 0, (size_t)N * sizeof(int), stream);
  hipMemsetAsync(pooled, 0, ((size_t)G * HIDDIM + G) * sizeof(float), stream);
  count_deg<<<eb, blk, 0, stream>>>(ei, deg, E, N);
  scan_deg<<<1, 1024, 0, stream>>>(deg, rowptr, N);
  fill_csr<<<eb, blk, 0, stream>>>(ei, rowptr, cursor, csr, E, N);

  // encoder
  gemm_bias_act<<<gemm_grid, blk, 0, stream>>>(x, enc_w, enc_b, h0, N, HIDDIM, DIN, 1);

  for (int L = 0; L < 2; ++L) {
    gemm_bias_act<<<gemm_grid, blk, 0, stream>>>(h0, g_wl[L], g_bl[L], xl, N, HIDDIM, HIDDIM, 0);
    gemm_bias_act<<<gemm_grid, blk, 0, stream>>>(h0, g_wr[L], g_br[L], xr, N, HIDDIM, HIDDIM, 0);
    if (L == 0) {
      node_gat<0><<<nb, blk, 0, stream>>>(xl, xr, ei, rowptr, csr, g_att[0], g_bias[0],
                                          ln_g, ln_b, nullptr, nullptr, nullptr, h0, E, N);
    } else {
      node_gat<1><<<nb, blk, 0, stream>>>(xl, xr, ei, rowptr, csr, g_att[1], g_bias[1],
                                          nullptr, nullptr, batch, pooled, counts, nullptr, E, N);
    }
  }
  head_kernel<<<1, blk, 0, stream>>>(pooled, counts, h1_w, h1_b, h2_w, h2_b, out, G, H1, OUT);
}

// Round 4
// 710.761 us; speedup vs baseline: 4.3126x; 1.2000x over previous
//
#include <hip/hip_runtime.h>

#define HIDDIM 256
#define NHEADS 8

// ---------------- GEMM: C[M,N] = act(A[M,K] @ W[K,N] + bias[N]) ----------------
__global__ __launch_bounds__(256) void gemm_bias_act(
    const float* __restrict__ A, const float* __restrict__ W,
    const float* __restrict__ bias, float* __restrict__ C,
    int M, int N, int K, int act) {
  __shared__ float As[16][65];
  __shared__ float Bs[16][64];
  const int tid = threadIdx.x;
  const int bm = blockIdx.y * 64, bn = blockIdx.x * 64;
  const int tx = tid & 15, ty = tid >> 4;
  float acc[4][4] = {};
  for (int k0 = 0; k0 < K; k0 += 16) {
    {
      const int m = tid >> 2;
      const int k = (tid & 3) * 4;
      const int gm = bm + m;
      float4 v = make_float4(0.f, 0.f, 0.f, 0.f);
      if (gm < M) v = *(const float4*)(A + (size_t)gm * K + k0 + k);
      As[k + 0][m] = v.x; As[k + 1][m] = v.y; As[k + 2][m] = v.z; As[k + 3][m] = v.w;
    }
    {
      const int n = (tid & 15) * 4;
      const int k = tid >> 4;
      *(float4*)&Bs[k][n] = *(const float4*)(W + (size_t)(k0 + k) * N + bn + n);
    }
    __syncthreads();
    #pragma unroll
    for (int kk = 0; kk < 16; ++kk) {
      float a[4], b[4];
      #pragma unroll
      for (int i = 0; i < 4; ++i) a[i] = As[kk][ty * 4 + i];
      #pragma unroll
      for (int j = 0; j < 4; ++j) b[j] = Bs[kk][tx * 4 + j];
      #pragma unroll
      for (int i = 0; i < 4; ++i)
        #pragma unroll
        for (int j = 0; j < 4; ++j) acc[i][j] = fmaf(a[i], b[j], acc[i][j]);
    }
    __syncthreads();
  }
  #pragma unroll
  for (int i = 0; i < 4; ++i) {
    const int gm = bm + ty * 4 + i;
    if (gm >= M) continue;
    #pragma unroll
    for (int j = 0; j < 4; ++j) {
      const int gn = bn + tx * 4 + j;
      float v = acc[i][j] + bias[gn];
      if (act == 1 && v < 0.f) v = 0.f;
      C[(size_t)gm * N + gn] = v;
    }
  }
}

// ---------------- CSR build (by destination; stores SRC node id) ----------------
__global__ __launch_bounds__(256) void count_deg(
    const int* __restrict__ ei, int* __restrict__ deg, int E, int Nn) {
  const int t = blockIdx.x * blockDim.x + threadIdx.x;
  const int ET = E + Nn;
  if (t >= ET) return;
  const int dst = (t < E) ? ei[E + t] : (t - E);
  atomicAdd(&deg[dst], 1);
}

__global__ __launch_bounds__(1024) void scan_deg(
    const int* __restrict__ deg, int* __restrict__ rowptr, int Nn) {
  __shared__ int lds[1024];
  __shared__ int carry;
  const int tid = threadIdx.x;
  if (tid == 0) { carry = 0; rowptr[0] = 0; }
  __syncthreads();
  for (int base = 0; base < Nn; base += 1024) {
    const int i = base + tid;
    int v = (i < Nn) ? deg[i] : 0;
    lds[tid] = v;
    __syncthreads();
    for (int off = 1; off < 1024; off <<= 1) {
      int t = (tid >= off) ? lds[tid - off] : 0;
      __syncthreads();
      lds[tid] += t;
      __syncthreads();
    }
    const int incl = lds[tid];
    const int c = carry;
    if (i < Nn) rowptr[i + 1] = incl + c;
    __syncthreads();
    if (tid == 0) carry = c + lds[1023];
    __syncthreads();
  }
}

__global__ __launch_bounds__(256) void fill_csr(
    const int* __restrict__ ei, const int* __restrict__ rowptr,
    int* __restrict__ cursor, int* __restrict__ csr, int E, int Nn) {
  const int t = blockIdx.x * blockDim.x + threadIdx.x;
  const int ET = E + Nn;
  if (t >= ET) return;
  int src, dst;
  if (t < E) { src = ei[t]; dst = ei[E + t]; }
  else { src = t - E; dst = t - E; }
  const int pos = atomicAdd(&cursor[dst], 1);
  csr[rowptr[dst] + pos] = src;
}

// ---------------- fused single-pass GATv2 per-node kernel ----------------
// one wave per node; lane covers channels [4*lane,4*lane+4); head h = lane>>3
// flash-style online softmax: (m, d, acc) updated per 4-edge block
// MODE 0: out = layernorm(relu(agg + bias)) -> outp[n]
// MODE 1: pooled[batch[n]] += relu(agg + bias); counts += 1
template <int MODE>
__global__ __launch_bounds__(256) void node_gat(
    const float* __restrict__ xl, const float* __restrict__ xr,
    const int* __restrict__ rowptr, const int* __restrict__ csr,
    const float* __restrict__ att, const float* __restrict__ bias,
    const float* __restrict__ lng, const float* __restrict__ lnb,
    const int* __restrict__ batch, float* __restrict__ pooled,
    float* __restrict__ counts, float* __restrict__ outp, int Nn) {
  int n = (int)((blockIdx.x * (size_t)blockDim.x + threadIdx.x) >> 6);
  const int lane = threadIdx.x & 63;
  if (n >= Nn) return;
  n = __builtin_amdgcn_readfirstlane(n);
  const int r0 = rowptr[n], r1 = rowptr[n + 1];
  const int jm = r1 - 1;
  const float4 xr4 = *(const float4*)(xr + (size_t)n * HIDDIM + lane * 4);
  const float4 at4 = *(const float4*)(att + lane * 4);

  float m = -1e30f, d = 0.f;
  float4 acc = make_float4(0.f, 0.f, 0.f, 0.f);

  for (int j0 = r0; j0 < r1; j0 += 4) {
    // 4 independent gathers (tail clamps to last edge; masked via -inf score)
    const int i0 = csr[j0];
    const int i1 = csr[j0 + 1 <= jm ? j0 + 1 : jm];
    const int i2 = csr[j0 + 2 <= jm ? j0 + 2 : jm];
    const int i3 = csr[j0 + 3 <= jm ? j0 + 3 : jm];
    const float4 a0 = *(const float4*)(xl + (size_t)i0 * HIDDIM + lane * 4);
    const float4 a1 = *(const float4*)(xl + (size_t)i1 * HIDDIM + lane * 4);
    const float4 a2 = *(const float4*)(xl + (size_t)i2 * HIDDIM + lane * 4);
    const float4 a3 = *(const float4*)(xl + (size_t)i3 * HIDDIM + lane * 4);

    float s0, s1, s2, s3;
    {
      float v;
      v = a0.x + xr4.x; v = v >= 0.f ? v : 0.2f * v; s0 = v * at4.x;
      v = a0.y + xr4.y; v = v >= 0.f ? v : 0.2f * v; s0 = fmaf(v, at4.y, s0);
      v = a0.z + xr4.z; v = v >= 0.f ? v : 0.2f * v; s0 = fmaf(v, at4.z, s0);
      v = a0.w + xr4.w; v = v >= 0.f ? v : 0.2f * v; s0 = fmaf(v, at4.w, s0);
      v = a1.x + xr4.x; v = v >= 0.f ? v : 0.2f * v; s1 = v * at4.x;
      v = a1.y + xr4.y; v = v >= 0.f ? v : 0.2f * v; s1 = fmaf(v, at4.y, s1);
      v = a1.z + xr4.z; v = v >= 0.f ? v : 0.2f * v; s1 = fmaf(v, at4.z, s1);
      v = a1.w + xr4.w; v = v >= 0.f ? v : 0.2f * v; s1 = fmaf(v, at4.w, s1);
      v = a2.x + xr4.x; v = v >= 0.f ? v : 0.2f * v; s2 = v * at4.x;
      v = a2.y + xr4.y; v = v >= 0.f ? v : 0.2f * v; s2 = fmaf(v, at4.y, s2);
      v = a2.z + xr4.z; v = v >= 0.f ? v : 0.2f * v; s2 = fmaf(v, at4.z, s2);
      v = a2.w + xr4.w; v = v >= 0.f ? v : 0.2f * v; s2 = fmaf(v, at4.w, s2);
      v = a3.x + xr4.x; v = v >= 0.f ? v : 0.2f * v; s3 = v * at4.x;
      v = a3.y + xr4.y; v = v >= 0.f ? v : 0.2f * v; s3 = fmaf(v, at4.y, s3);
      v = a3.z + xr4.z; v = v >= 0.f ? v : 0.2f * v; s3 = fmaf(v, at4.z, s3);
      v = a3.w + xr4.w; v = v >= 0.f ? v : 0.2f * v; s3 = fmaf(v, at4.w, s3);
    }
    // 8-lane head-group reduction for each of the 4 scores
    s0 += __shfl_xor(s0, 1); s0 += __shfl_xor(s0, 2); s0 += __shfl_xor(s0, 4);
    s1 += __shfl_xor(s1, 1); s1 += __shfl_xor(s1, 2); s1 += __shfl_xor(s1, 4);
    s2 += __shfl_xor(s2, 1); s2 += __shfl_xor(s2, 2); s2 += __shfl_xor(s2, 4);
    s3 += __shfl_xor(s3, 1); s3 += __shfl_xor(s3, 2); s3 += __shfl_xor(s3, 4);
    if (j0 + 1 > jm) s1 = -1e30f;
    if (j0 + 2 > jm) s2 = -1e30f;
    if (j0 + 3 > jm) s3 = -1e30f;

    const float mb = fmaxf(fmaxf(fmaxf(s0, s1), fmaxf(s2, s3)), m);
    const float scale = __expf(m - mb);
    const float w0 = __expf(s0 - mb);
    const float w1 = __expf(s1 - mb);
    const float w2 = __expf(s2 - mb);
    const float w3 = __expf(s3 - mb);
    d = fmaf(d, scale, (w0 + w1) + (w2 + w3));
    acc.x = fmaf(acc.x, scale, fmaf(w0, a0.x, fmaf(w1, a1.x, fmaf(w2, a2.x, w3 * a3.x))));
    acc.y = fmaf(acc.y, scale, fmaf(w0, a0.y, fmaf(w1, a1.y, fmaf(w2, a2.y, w3 * a3.y))));
    acc.z = fmaf(acc.z, scale, fmaf(w0, a0.z, fmaf(w1, a1.z, fmaf(w2, a2.z, w3 * a3.z))));
    acc.w = fmaf(acc.w, scale, fmaf(w0, a0.w, fmaf(w1, a1.w, fmaf(w2, a2.w, w3 * a3.w))));
    m = mb;
  }
  const float inv_d = 1.f / d;

  // epilogue: bias + relu
  const float4 bb = *(const float4*)(bias + lane * 4);
  float t0 = fmaf(acc.x, inv_d, bb.x); t0 = t0 > 0.f ? t0 : 0.f;
  float t1 = fmaf(acc.y, inv_d, bb.y); t1 = t1 > 0.f ? t1 : 0.f;
  float t2 = fmaf(acc.z, inv_d, bb.z); t2 = t2 > 0.f ? t2 : 0.f;
  float t3 = fmaf(acc.w, inv_d, bb.w); t3 = t3 > 0.f ? t3 : 0.f;

  if (MODE == 0) {
    float s = t0 + t1 + t2 + t3;
    #pragma unroll
    for (int mm = 1; mm < 64; mm <<= 1) s += __shfl_xor(s, mm);
    const float mu = s * (1.f / HIDDIM);
    const float d0 = t0 - mu, d1 = t1 - mu, d2 = t2 - mu, d3 = t3 - mu;
    float q = d0 * d0 + d1 * d1 + d2 * d2 + d3 * d3;
    #pragma unroll
    for (int mm = 1; mm < 64; mm <<= 1) q += __shfl_xor(q, mm);
    const float inv = rsqrtf(q * (1.f / HIDDIM) + 1e-5f);
    const float4 g4 = *(const float4*)(lng + lane * 4);
    const float4 b4 = *(const float4*)(lnb + lane * 4);
    float4 o;
    o.x = d0 * inv * g4.x + b4.x;
    o.y = d1 * inv * g4.y + b4.y;
    o.z = d2 * inv * g4.z + b4.z;
    o.w = d3 * inv * g4.w + b4.w;
    *(float4*)(outp + (size_t)n * HIDDIM + lane * 4) = o;
  } else {
    const int g = batch[n];
    float* p = pooled + (size_t)g * HIDDIM + lane * 4;
    atomicAdd(p + 0, t0);
    atomicAdd(p + 1, t1);
    atomicAdd(p + 2, t2);
    atomicAdd(p + 3, t3);
    if (lane == 0) atomicAdd(&counts[g], 1.f);
  }
}

// ---------------- head MLP ----------------
__global__ __launch_bounds__(256) void head_kernel(
    const float* __restrict__ pooled, const float* __restrict__ counts,
    const float* __restrict__ h1w, const float* __restrict__ h1b,
    const float* __restrict__ h2w, const float* __restrict__ h2b,
    float* __restrict__ out, int G, int H1, int OUT) {
  __shared__ float P[16][HIDDIM];
  __shared__ float Hh[16][128];
  const int tid = threadIdx.x;
  for (int i = tid; i < G * HIDDIM; i += 256) {
    const int g = i / HIDDIM, c = i % HIDDIM;
    float cnt = counts[g];
    if (cnt < 1.f) cnt = 1.f;
    P[g][c] = pooled[i] / cnt;
  }
  __syncthreads();
  for (int i = tid; i < G * H1; i += 256) {
    const int g = i / H1, j = i % H1;
    float s = h1b[j];
    for (int k = 0; k < HIDDIM; ++k) s = fmaf(P[g][k], h1w[k * H1 + j], s);
    Hh[g][j] = s > 0.f ? s : 0.f;
  }
  __syncthreads();
  for (int i = tid; i < G * OUT; i += 256) {
    const int g = i / OUT, o = i % OUT;
    float s = h2b[o];
    for (int k = 0; k < H1; ++k) s = fmaf(Hh[g][k], h2w[k * OUT + o], s);
    out[i] = s;
  }
}

extern "C" void kernel_launch(void* const* d_in, const int* in_sizes, int n_in,
                              void* d_out, int out_size, void* d_ws, size_t ws_size,
                              hipStream_t stream) {
  const float* x = (const float*)d_in[0];
  const int* ei = (const int*)d_in[1];
  const int* batch = (const int*)d_in[2];
  const float* enc_w = (const float*)d_in[3];
  const float* enc_b = (const float*)d_in[4];
  const float* g_wl[2] = {(const float*)d_in[5], (const float*)d_in[11]};
  const float* g_bl[2] = {(const float*)d_in[6], (const float*)d_in[12]};
  const float* g_wr[2] = {(const float*)d_in[7], (const float*)d_in[13]};
  const float* g_br[2] = {(const float*)d_in[8], (const float*)d_in[14]};
  const float* g_att[2] = {(const float*)d_in[9], (const float*)d_in[15]};
  const float* g_bias[2] = {(const float*)d_in[10], (const float*)d_in[16]};
  const float* ln_g = (const float*)d_in[17];
  const float* ln_b = (const float*)d_in[18];
  const float* h1_w = (const float*)d_in[19];
  const float* h1_b = (const float*)d_in[20];
  const float* h2_w = (const float*)d_in[21];
  const float* h2_b = (const float*)d_in[22];
  float* out = (float*)d_out;

  const int N = in_sizes[2];          // 20000
  const int E = in_sizes[1] / 2;      // 320000
  const int DIN = in_sizes[0] / N;    // 128
  const int ET = E + N;
  const int H1 = in_sizes[20];        // 128
  const int OUT = in_sizes[22];       // 2
  const int G = out_size / OUT;       // 16

  float* ws = (float*)d_ws;
  const size_t NH = (size_t)N * HIDDIM;
  float* h0 = ws;
  float* xl = h0 + NH;
  float* xr = xl + NH;
  float* pooled = xr + NH;                                  // [G,256]
  float* counts = pooled + (size_t)G * HIDDIM;              // [G]
  int* deg = (int*)(counts + G);                            // [N]
  int* rowptr = deg + N;                                    // [N+1]
  int* cursor = rowptr + (N + 1);                           // [N]
  int* csr = cursor + N;                                    // [ET]

  const dim3 blk(256);
  const dim3 gemm_grid(HIDDIM / 64, (N + 63) / 64);
  const int eb = (ET + 255) / 256;
  const int nb = (N + 3) / 4;

  // CSR build (graph identical for both layers)
  hipMemsetAsync(deg, 0, (size_t)N * sizeof(int), stream);
  hipMemsetAsync(cursor, 0, (size_t)N * sizeof(int), stream);
  hipMemsetAsync(pooled, 0, ((size_t)G * HIDDIM + G) * sizeof(float), stream);
  count_deg<<<eb, blk, 0, stream>>>(ei, deg, E, N);
  scan_deg<<<1, 1024, 0, stream>>>(deg, rowptr, N);
  fill_csr<<<eb, blk, 0, stream>>>(ei, rowptr, cursor, csr, E, N);

  // encoder
  gemm_bias_act<<<gemm_grid, blk, 0, stream>>>(x, enc_w, enc_b, h0, N, HIDDIM, DIN, 1);

  for (int L = 0; L < 2; ++L) {
    gemm_bias_act<<<gemm_grid, blk, 0, stream>>>(h0, g_wl[L], g_bl[L], xl, N, HIDDIM, HIDDIM, 0);
    gemm_bias_act<<<gemm_grid, blk, 0, stream>>>(h0, g_wr[L], g_br[L], xr, N, HIDDIM, HIDDIM, 0);
    if (L == 0) {
      node_gat<0><<<nb, blk, 0, stream>>>(xl, xr, rowptr, csr, g_att[0], g_bias[0],
                                          ln_g, ln_b, nullptr, nullptr, nullptr, h0, N);
    } else {
      node_gat<1><<<nb, blk, 0, stream>>>(xl, xr, rowptr, csr, g_att[1], g_bias[1],
                                          nullptr, nullptr, batch, pooled, counts, nullptr, N);
    }
  }
  head_kernel<<<1, blk, 0, stream>>>(pooled, counts, h1_w, h1_b, h2_w, h2_b, out, G, H1, OUT);
}

// Round 5
// 700.295 us; speedup vs baseline: 4.3770x; 1.0149x over previous
//
#include <hip/hip_runtime.h>

#define HIDDIM 256
#define NHEADS 8

// ---------------- GEMM: C[M,N] = act(A[M,K] @ W[K,N] + bias[N]) ----------------
__global__ __launch_bounds__(256) void gemm_bias_act(
    const float* __restrict__ A, const float* __restrict__ W,
    const float* __restrict__ bias, float* __restrict__ C,
    int M, int N, int K, int act) {
  __shared__ float As[16][65];
  __shared__ float Bs[16][64];
  const int tid = threadIdx.x;
  const int bm = blockIdx.y * 64, bn = blockIdx.x * 64;
  const int tx = tid & 15, ty = tid >> 4;
  float acc[4][4] = {};
  for (int k0 = 0; k0 < K; k0 += 16) {
    {
      const int m = tid >> 2;
      const int k = (tid & 3) * 4;
      const int gm = bm + m;
      float4 v = make_float4(0.f, 0.f, 0.f, 0.f);
      if (gm < M) v = *(const float4*)(A + (size_t)gm * K + k0 + k);
      As[k + 0][m] = v.x; As[k + 1][m] = v.y; As[k + 2][m] = v.z; As[k + 3][m] = v.w;
    }
    {
      const int n = (tid & 15) * 4;
      const int k = tid >> 4;
      *(float4*)&Bs[k][n] = *(const float4*)(W + (size_t)(k0 + k) * N + bn + n);
    }
    __syncthreads();
    #pragma unroll
    for (int kk = 0; kk < 16; ++kk) {
      float a[4], b[4];
      #pragma unroll
      for (int i = 0; i < 4; ++i) a[i] = As[kk][ty * 4 + i];
      #pragma unroll
      for (int j = 0; j < 4; ++j) b[j] = Bs[kk][tx * 4 + j];
      #pragma unroll
      for (int i = 0; i < 4; ++i)
        #pragma unroll
        for (int j = 0; j < 4; ++j) acc[i][j] = fmaf(a[i], b[j], acc[i][j]);
    }
    __syncthreads();
  }
  #pragma unroll
  for (int i = 0; i < 4; ++i) {
    const int gm = bm + ty * 4 + i;
    if (gm >= M) continue;
    #pragma unroll
    for (int j = 0; j < 4; ++j) {
      const int gn = bn + tx * 4 + j;
      float v = acc[i][j] + bias[gn];
      if (act == 1 && v < 0.f) v = 0.f;
      C[(size_t)gm * N + gn] = v;
    }
  }
}

// ---------------- CSR build (by destination; stores SRC node id) ----------------
__global__ __launch_bounds__(256) void count_deg(
    const int* __restrict__ ei, int* __restrict__ deg, int E, int Nn) {
  const int t = blockIdx.x * blockDim.x + threadIdx.x;
  const int ET = E + Nn;
  if (t >= ET) return;
  const int dst = (t < E) ? ei[E + t] : (t - E);
  atomicAdd(&deg[dst], 1);
}

// hierarchical scan: wave shuffles + per-chunk wave-sum scan (4 barriers/chunk)
__global__ __launch_bounds__(1024) void scan_deg(
    const int* __restrict__ deg, int* __restrict__ rowptr, int Nn) {
  __shared__ int wsum[16];
  __shared__ int carry_s;
  const int tid = threadIdx.x;
  const int wid = tid >> 6, lane = tid & 63;
  if (tid == 0) { carry_s = 0; rowptr[0] = 0; }
  __syncthreads();
  for (int base = 0; base < Nn; base += 1024) {
    const int i = base + tid;
    int s = (i < Nn) ? deg[i] : 0;
    #pragma unroll
    for (int off = 1; off < 64; off <<= 1) {
      int t = __shfl_up(s, off);
      if (lane >= off) s += t;
    }
    if (lane == 63) wsum[wid] = s;
    __syncthreads();
    if (wid == 0 && lane < 16) {
      int ws = wsum[lane];
      #pragma unroll
      for (int off = 1; off < 16; off <<= 1) {
        int t = __shfl_up(ws, off);
        if (lane >= off) ws += t;
      }
      wsum[lane] = ws;
    }
    __syncthreads();
    const int prefix = (wid > 0 ? wsum[wid - 1] : 0) + carry_s;
    if (i < Nn) rowptr[i + 1] = s + prefix;
    __syncthreads();
    if (tid == 0) carry_s += wsum[15];
    __syncthreads();
  }
}

__global__ __launch_bounds__(256) void fill_csr(
    const int* __restrict__ ei, const int* __restrict__ rowptr,
    int* __restrict__ cursor, int* __restrict__ csr, int E, int Nn) {
  const int t = blockIdx.x * blockDim.x + threadIdx.x;
  const int ET = E + Nn;
  if (t >= ET) return;
  int src, dst;
  if (t < E) { src = ei[t]; dst = ei[E + t]; }
  else { src = t - E; dst = t - E; }
  const int pos = atomicAdd(&cursor[dst], 1);
  csr[rowptr[dst] + pos] = src;
}

// ---------------- fused single-pass GATv2 per-node kernel, 2-stage pipelined ----------------
// one wave per node; lane covers channels [4*lane,4*lane+4); head h = lane>>3
template <int MODE>
__global__ __launch_bounds__(256) void node_gat(
    const float* __restrict__ xl, const float* __restrict__ xr,
    const int* __restrict__ rowptr, const int* __restrict__ csr,
    const float* __restrict__ att, const float* __restrict__ bias,
    const float* __restrict__ lng, const float* __restrict__ lnb,
    const int* __restrict__ batch, float* __restrict__ pooled,
    float* __restrict__ counts, float* __restrict__ outp, int Nn) {
  int n = (int)((blockIdx.x * (size_t)blockDim.x + threadIdx.x) >> 6);
  const int lane = threadIdx.x & 63;
  if (n >= Nn) return;
  n = __builtin_amdgcn_readfirstlane(n);
  const int r0 = rowptr[n], r1 = rowptr[n + 1];
  const int jm = r1 - 1;
  const float4* __restrict__ xlv = (const float4*)xl;
  const float4 xr4 = *(const float4*)(xr + (size_t)n * HIDDIM + lane * 4);
  const float4 at4 = *(const float4*)(att + lane * 4);

  float m = -1e30f, d = 0.f;
  float4 acc = make_float4(0.f, 0.f, 0.f, 0.f);

  // prologue: issue rows for first 4-edge block (tail edges clamp to jm)
  int j0 = r0;
  {
    // nothing
  }
  int ja = j0 + 1 <= jm ? j0 + 1 : jm;
  int jb = j0 + 2 <= jm ? j0 + 2 : jm;
  int jc = j0 + 3 <= jm ? j0 + 3 : jm;
  float4 a0 = xlv[(size_t)csr[j0] * (HIDDIM / 4) + lane];
  float4 a1 = xlv[(size_t)csr[ja] * (HIDDIM / 4) + lane];
  float4 a2 = xlv[(size_t)csr[jb] * (HIDDIM / 4) + lane];
  float4 a3 = xlv[(size_t)csr[jc] * (HIDDIM / 4) + lane];

  while (true) {
    const int jn = j0 + 4;
    const bool have_next = jn <= jm;     // wave-uniform
    float4 c0, c1, c2, c3;
    if (have_next) {
      // issue next block's gathers BEFORE processing current block
      const int ka = jn + 1 <= jm ? jn + 1 : jm;
      const int kb = jn + 2 <= jm ? jn + 2 : jm;
      const int kc = jn + 3 <= jm ? jn + 3 : jm;
      c0 = xlv[(size_t)csr[jn] * (HIDDIM / 4) + lane];
      c1 = xlv[(size_t)csr[ka] * (HIDDIM / 4) + lane];
      c2 = xlv[(size_t)csr[kb] * (HIDDIM / 4) + lane];
      c3 = xlv[(size_t)csr[kc] * (HIDDIM / 4) + lane];
    }

    float s0, s1, s2, s3;
    {
      float v;
      v = a0.x + xr4.x; v = v >= 0.f ? v : 0.2f * v; s0 = v * at4.x;
      v = a0.y + xr4.y; v = v >= 0.f ? v : 0.2f * v; s0 = fmaf(v, at4.y, s0);
      v = a0.z + xr4.z; v = v >= 0.f ? v : 0.2f * v; s0 = fmaf(v, at4.z, s0);
      v = a0.w + xr4.w; v = v >= 0.f ? v : 0.2f * v; s0 = fmaf(v, at4.w, s0);
      v = a1.x + xr4.x; v = v >= 0.f ? v : 0.2f * v; s1 = v * at4.x;
      v = a1.y + xr4.y; v = v >= 0.f ? v : 0.2f * v; s1 = fmaf(v, at4.y, s1);
      v = a1.z + xr4.z; v = v >= 0.f ? v : 0.2f * v; s1 = fmaf(v, at4.z, s1);
      v = a1.w + xr4.w; v = v >= 0.f ? v : 0.2f * v; s1 = fmaf(v, at4.w, s1);
      v = a2.x + xr4.x; v = v >= 0.f ? v : 0.2f * v; s2 = v * at4.x;
      v = a2.y + xr4.y; v = v >= 0.f ? v : 0.2f * v; s2 = fmaf(v, at4.y, s2);
      v = a2.z + xr4.z; v = v >= 0.f ? v : 0.2f * v; s2 = fmaf(v, at4.z, s2);
      v = a2.w + xr4.w; v = v >= 0.f ? v : 0.2f * v; s2 = fmaf(v, at4.w, s2);
      v = a3.x + xr4.x; v = v >= 0.f ? v : 0.2f * v; s3 = v * at4.x;
      v = a3.y + xr4.y; v = v >= 0.f ? v : 0.2f * v; s3 = fmaf(v, at4.y, s3);
      v = a3.z + xr4.z; v = v >= 0.f ? v : 0.2f * v; s3 = fmaf(v, at4.z, s3);
      v = a3.w + xr4.w; v = v >= 0.f ? v : 0.2f * v; s3 = fmaf(v, at4.w, s3);
    }
    s0 += __shfl_xor(s0, 1); s0 += __shfl_xor(s0, 2); s0 += __shfl_xor(s0, 4);
    s1 += __shfl_xor(s1, 1); s1 += __shfl_xor(s1, 2); s1 += __shfl_xor(s1, 4);
    s2 += __shfl_xor(s2, 1); s2 += __shfl_xor(s2, 2); s2 += __shfl_xor(s2, 4);
    s3 += __shfl_xor(s3, 1); s3 += __shfl_xor(s3, 2); s3 += __shfl_xor(s3, 4);
    if (j0 + 1 > jm) s1 = -1e30f;
    if (j0 + 2 > jm) s2 = -1e30f;
    if (j0 + 3 > jm) s3 = -1e30f;

    const float mb = fmaxf(fmaxf(fmaxf(s0, s1), fmaxf(s2, s3)), m);
    const float scale = __expf(m - mb);
    const float w0 = __expf(s0 - mb);
    const float w1 = __expf(s1 - mb);
    const float w2 = __expf(s2 - mb);
    const float w3 = __expf(s3 - mb);
    d = fmaf(d, scale, (w0 + w1) + (w2 + w3));
    acc.x = fmaf(acc.x, scale, fmaf(w0, a0.x, fmaf(w1, a1.x, fmaf(w2, a2.x, w3 * a3.x))));
    acc.y = fmaf(acc.y, scale, fmaf(w0, a0.y, fmaf(w1, a1.y, fmaf(w2, a2.y, w3 * a3.y))));
    acc.z = fmaf(acc.z, scale, fmaf(w0, a0.z, fmaf(w1, a1.z, fmaf(w2, a2.z, w3 * a3.z))));
    acc.w = fmaf(acc.w, scale, fmaf(w0, a0.w, fmaf(w1, a1.w, fmaf(w2, a2.w, w3 * a3.w))));
    m = mb;

    if (!have_next) break;
    a0 = c0; a1 = c1; a2 = c2; a3 = c3;
    j0 = jn;
  }
  const float inv_d = 1.f / d;

  // epilogue: bias + relu
  const float4 bb = *(const float4*)(bias + lane * 4);
  float t0 = fmaf(acc.x, inv_d, bb.x); t0 = t0 > 0.f ? t0 : 0.f;
  float t1 = fmaf(acc.y, inv_d, bb.y); t1 = t1 > 0.f ? t1 : 0.f;
  float t2 = fmaf(acc.z, inv_d, bb.z); t2 = t2 > 0.f ? t2 : 0.f;
  float t3 = fmaf(acc.w, inv_d, bb.w); t3 = t3 > 0.f ? t3 : 0.f;

  if (MODE == 0) {
    float s = t0 + t1 + t2 + t3;
    #pragma unroll
    for (int mm = 1; mm < 64; mm <<= 1) s += __shfl_xor(s, mm);
    const float mu = s * (1.f / HIDDIM);
    const float d0 = t0 - mu, d1 = t1 - mu, d2 = t2 - mu, d3 = t3 - mu;
    float q = d0 * d0 + d1 * d1 + d2 * d2 + d3 * d3;
    #pragma unroll
    for (int mm = 1; mm < 64; mm <<= 1) q += __shfl_xor(q, mm);
    const float inv = rsqrtf(q * (1.f / HIDDIM) + 1e-5f);
    const float4 g4 = *(const float4*)(lng + lane * 4);
    const float4 b4 = *(const float4*)(lnb + lane * 4);
    float4 o;
    o.x = d0 * inv * g4.x + b4.x;
    o.y = d1 * inv * g4.y + b4.y;
    o.z = d2 * inv * g4.z + b4.z;
    o.w = d3 * inv * g4.w + b4.w;
    *(float4*)(outp + (size_t)n * HIDDIM + lane * 4) = o;
  } else {
    const int g = batch[n];
    float* p = pooled + (size_t)g * HIDDIM + lane * 4;
    atomicAdd(p + 0, t0);
    atomicAdd(p + 1, t1);
    atomicAdd(p + 2, t2);
    atomicAdd(p + 3, t3);
    if (lane == 0) atomicAdd(&counts[g], 1.f);
  }
}

// ---------------- head MLP ----------------
__global__ __launch_bounds__(256) void head_kernel(
    const float* __restrict__ pooled, const float* __restrict__ counts,
    const float* __restrict__ h1w, const float* __restrict__ h1b,
    const float* __restrict__ h2w, const float* __restrict__ h2b,
    float* __restrict__ out, int G, int H1, int OUT) {
  __shared__ float P[16][HIDDIM];
  __shared__ float Hh[16][128];
  const int tid = threadIdx.x;
  for (int i = tid; i < G * HIDDIM; i += 256) {
    const int g = i / HIDDIM, c = i % HIDDIM;
    float cnt = counts[g];
    if (cnt < 1.f) cnt = 1.f;
    P[g][c] = pooled[i] / cnt;
  }
  __syncthreads();
  for (int i = tid; i < G * H1; i += 256) {
    const int g = i / H1, j = i % H1;
    float s = h1b[j];
    for (int k = 0; k < HIDDIM; ++k) s = fmaf(P[g][k], h1w[k * H1 + j], s);
    Hh[g][j] = s > 0.f ? s : 0.f;
  }
  __syncthreads();
  for (int i = tid; i < G * OUT; i += 256) {
    const int g = i / OUT, o = i % OUT;
    float s = h2b[o];
    for (int k = 0; k < H1; ++k) s = fmaf(Hh[g][k], h2w[k * OUT + o], s);
    out[i] = s;
  }
}

extern "C" void kernel_launch(void* const* d_in, const int* in_sizes, int n_in,
                              void* d_out, int out_size, void* d_ws, size_t ws_size,
                              hipStream_t stream) {
  const float* x = (const float*)d_in[0];
  const int* ei = (const int*)d_in[1];
  const int* batch = (const int*)d_in[2];
  const float* enc_w = (const float*)d_in[3];
  const float* enc_b = (const float*)d_in[4];
  const float* g_wl[2] = {(const float*)d_in[5], (const float*)d_in[11]};
  const float* g_bl[2] = {(const float*)d_in[6], (const float*)d_in[12]};
  const float* g_wr[2] = {(const float*)d_in[7], (const float*)d_in[13]};
  const float* g_br[2] = {(const float*)d_in[8], (const float*)d_in[14]};
  const float* g_att[2] = {(const float*)d_in[9], (const float*)d_in[15]};
  const float* g_bias[2] = {(const float*)d_in[10], (const float*)d_in[16]};
  const float* ln_g = (const float*)d_in[17];
  const float* ln_b = (const float*)d_in[18];
  const float* h1_w = (const float*)d_in[19];
  const float* h1_b = (const float*)d_in[20];
  const float* h2_w = (const float*)d_in[21];
  const float* h2_b = (const float*)d_in[22];
  float* out = (float*)d_out;

  const int N = in_sizes[2];          // 20000
  const int E = in_sizes[1] / 2;      // 320000
  const int DIN = in_sizes[0] / N;    // 128
  const int ET = E + N;
  const int H1 = in_sizes[20];        // 128
  const int OUT = in_sizes[22];       // 2
  const int G = out_size / OUT;       // 16

  float* ws = (float*)d_ws;
  const size_t NH = (size_t)N * HIDDIM;
  float* h0 = ws;
  float* xl = h0 + NH;
  float* xr = xl + NH;
  float* pooled = xr + NH;                                  // [G,256]
  float* counts = pooled + (size_t)G * HIDDIM;              // [G]
  int* deg = (int*)(counts + G);                            // [N]
  int* rowptr = deg + N;                                    // [N+1]
  int* cursor = rowptr + (N + 1);                           // [N]
  int* csr = cursor + N;                                    // [ET]

  const dim3 blk(256);
  const dim3 gemm_grid(HIDDIM / 64, (N + 63) / 64);
  const int eb = (ET + 255) / 256;
  const int nb = (N + 3) / 4;

  // CSR build (graph identical for both layers)
  hipMemsetAsync(deg, 0, (size_t)N * sizeof(int), stream);
  hipMemsetAsync(cursor, 0, (size_t)N * sizeof(int), stream);
  hipMemsetAsync(pooled, 0, ((size_t)G * HIDDIM + G) * sizeof(float), stream);
  count_deg<<<eb, blk, 0, stream>>>(ei, deg, E, N);
  scan_deg<<<1, 1024, 0, stream>>>(deg, rowptr, N);
  fill_csr<<<eb, blk, 0, stream>>>(ei, rowptr, cursor, csr, E, N);

  // encoder
  gemm_bias_act<<<gemm_grid, blk, 0, stream>>>(x, enc_w, enc_b, h0, N, HIDDIM, DIN, 1);

  for (int L = 0; L < 2; ++L) {
    gemm_bias_act<<<gemm_grid, blk, 0, stream>>>(h0, g_wl[L], g_bl[L], xl, N, HIDDIM, HIDDIM, 0);
    gemm_bias_act<<<gemm_grid, blk, 0, stream>>>(h0, g_wr[L], g_br[L], xr, N, HIDDIM, HIDDIM, 0);
    if (L == 0) {
      node_gat<0><<<nb, blk, 0, stream>>>(xl, xr, rowptr, csr, g_att[0], g_bias[0],
                                          ln_g, ln_b, nullptr, nullptr, nullptr, h0, N);
    } else {
      node_gat<1><<<nb, blk, 0, stream>>>(xl, xr, rowptr, csr, g_att[1], g_bias[1],
                                          nullptr, nullptr, batch, pooled, counts, nullptr, N);
    }
  }
  head_kernel<<<1, blk, 0, stream>>>(pooled, counts, h1_w, h1_b, h2_w, h2_b, out, G, H1, OUT);
}